// Round 17
// baseline (1578.140 us; speedup 1.0000x reference)
//
#include <hip/hip_runtime.h>
#include <hip/hip_bf16.h>
#include <hip/hip_fp16.h>
#include <math.h>

// ---- problem constants ----
#define Bsz   32
#define Ssz   512
#define Fsz   40
#define Dsz   512
#define Hh    8
#define Lnum  4
#define Tsz   513           // S + 1 (cls token)
#define DKsz  256
#define DVsz  512
#define HKsz  32
#define HVsz  64
#define Msz   (Bsz*Tsz)     // 16416 rows
#define Mpad  16512         // 129*128, padded row count for 128-tiles
#define MLPsz 2048
#define NCH   32            // scan chunks per (b,h)
#define CSZ   17            // chunk size (last real chunk = 3; chunk 31 empty)
#define QKVG  1536          // packed q|k|v|g GEMM width
#define VOFFH 8404992       // half offset of vP within qkPh block (256*513*64)

typedef __attribute__((ext_vector_type(4))) float f32x4;
typedef __attribute__((ext_vector_type(8))) short bf16x8;

__device__ __forceinline__ float bf2f(short s) {
  unsigned int u = ((unsigned int)(unsigned short)s) << 16;
  return __builtin_bit_cast(float, u);
}
__device__ __forceinline__ short f2bf(float f) {
  __hip_bfloat16 b = __float2bfloat16(f);
  return __builtin_bit_cast(short, b);
}

// fast exact-enough GELU: A&S 7.1.26 3-term erf (max abs err 2.5e-5)
__device__ __forceinline__ float gelu_fast(float x) {
  float z = x * 0.70710678118654752f;
  float az = fabsf(z);
  float t = 1.f / (1.f + 0.47047f * az);
  float poly = t * (0.3480242f + t * (-0.0958798f + t * 0.7478556f));
  float erfa = 1.f - poly * __expf(-az * az);
  float er = copysignf(erfa, z);
  return 0.5f * x * (1.f + er);
}

__device__ __forceinline__ float wave_sum(float v) {
#pragma unroll
  for (int off = 32; off > 0; off >>= 1) v += __shfl_xor(v, off, 64);
  return v;
}

// ---- positional encoding table (T x D) ----
__global__ void pos_kernel(float* __restrict__ pos) {
  int idx = blockIdx.x * 256 + threadIdx.x;
  if (idx >= Tsz * Dsz) return;
  int t = idx / Dsz, d = idx % Dsz;
  float e = (float)(2 * (d >> 1)) / (float)Dsz;
  float den = powf(10000.f, e);
  float a = (float)t / den;
  pos[idx] = (d & 1) ? cosf(a) : sinf(a);
}

// ---- BiN temporal stats: per (b,f) mean + 1/std over S (ddof=1) ----
__global__ void tstat_kernel(const float* __restrict__ x,
                             float* __restrict__ mt, float* __restrict__ rst) {
  int bf = blockIdx.x;
  int b = bf / Fsz, f = bf % Fsz;
  int lane = threadIdx.x;
  const float* xp = x + (size_t)b * Ssz * Fsz + f;
  float s = 0.f, sq = 0.f;
  for (int i = lane; i < Ssz; i += 64) {
    float v = xp[(size_t)i * Fsz];
    s += v; sq += v * v;
  }
  s = wave_sum(s); sq = wave_sum(sq);
  if (lane == 0) {
    float m = s / (float)Ssz;
    float var = (sq - (float)Ssz * m * m) / (float)(Ssz - 1);
    float st = sqrtf(fmaxf(var, 0.f));
    if (st < 1e-4f) st = 1.f;
    mt[bf] = m;
    rst[bf] = 1.f / st;
  }
}

// ---- BiN both norms -> xbT[f][row] (transposed, fp32); zero cls/pad rows ----
__global__ __launch_bounds__(64) void binorm_kernel(
    const float* __restrict__ x, const float* __restrict__ l1,
    const float* __restrict__ b1, const float* __restrict__ l2,
    const float* __restrict__ b2, const float* __restrict__ y1p,
    const float* __restrict__ y2p, const float* __restrict__ mt,
    const float* __restrict__ rst, float* __restrict__ xbT) {
  int row = blockIdx.x;              // 0..Mpad-1
  int lane = threadIdx.x;
  int b = row / Tsz, t = row % Tsz;
  bool valid = (row < Msz) && (t < Ssz);
  if (!valid) {
    if (lane < Fsz) xbT[(size_t)lane * Mpad + row] = 0.f;
    return;
  }
  float xv = 0.f;
  const float* xp = x + ((size_t)b * Ssz + t) * Fsz;
  if (lane < Fsz) xv = xp[lane];
  float s  = wave_sum(lane < Fsz ? xv : 0.f);
  float sq = wave_sum(lane < Fsz ? xv * xv : 0.f);
  float m = s / (float)Fsz;
  float var = (sq - (float)Fsz * m * m) / (float)(Fsz - 1);
  float sf = sqrtf(fmaxf(var, 0.f));
  if (sf < 1e-4f) sf = 1.f;
  if (lane < Fsz) {
    float y1 = y1p[0], y2 = y2p[0];
    float z1 = (xv - m) / sf;
    float X1 = l1[t] * z1 + b1[t];
    int bf = b * Fsz + lane;
    float z2 = (xv - mt[bf]) * rst[bf];
    float X2 = l2[lane] * z2 + b2[lane];
    xbT[(size_t)lane * Mpad + row] = y1 * X1 + y2 * X2;
  }
}

// ---- embed GEMM: h[row][d] = xbT^T @ emb_w + emb_b + pos (cls rows special) ----
__global__ __launch_bounds__(256, 4) void embgemm_kernel(
    const float* __restrict__ xbT, const float* __restrict__ emb_w,
    const float* __restrict__ emb_b, const float* __restrict__ cls,
    const float* __restrict__ pos, float* __restrict__ h) {
  __shared__ float as[Fsz][64];
  __shared__ float bs[Fsz][64];
  int tid = threadIdx.x, tx = tid & 15, ty = tid >> 4;
  int r0 = blockIdx.x * 64, c0 = blockIdx.y * 64;
  for (int idx = tid; idx < Fsz * 64; idx += 256) {
    int f = idx >> 6, r = idx & 63;
    as[f][r] = xbT[(size_t)f * Mpad + r0 + r];
    bs[f][r] = emb_w[f * Dsz + c0 + r];
  }
  __syncthreads();
  float acc[4][4] = {};
#pragma unroll 5
  for (int f = 0; f < Fsz; ++f) {
    float4 a = *(const float4*)&as[f][ty * 4];
    float4 bv = *(const float4*)&bs[f][tx * 4];
    float av[4] = {a.x, a.y, a.z, a.w};
    float bw[4] = {bv.x, bv.y, bv.z, bv.w};
#pragma unroll
    for (int i = 0; i < 4; ++i)
#pragma unroll
      for (int j = 0; j < 4; ++j) acc[i][j] += av[i] * bw[j];
  }
#pragma unroll
  for (int i = 0; i < 4; ++i) {
    int gm = r0 + ty * 4 + i;
    int t = gm % Tsz;
    const float* pp = pos + (size_t)t * Dsz;
    bool iscls = (t == Ssz);
    int gn = c0 + tx * 4;
#pragma unroll
    for (int j = 0; j < 4; ++j) {
      float v = iscls ? (cls[gn + j] + pp[gn + j])
                      : (acc[i][j] + emb_b[gn + j] + pp[gn + j]);
      h[(size_t)gm * Dsz + gn + j] = v;
    }
  }
}

// ---- LayerNorm over D=512 (fp32 in, bf16 out) ----
__global__ __launch_bounds__(64) void ln_kernel(
    const float* __restrict__ in, const float* __restrict__ w,
    const float* __restrict__ b, short* __restrict__ out) {
  int row = blockIdx.x, lane = threadIdx.x;
  const float* p = in + (size_t)row * Dsz;
  float4 v0 = *(const float4*)(p + lane * 8);
  float4 v1 = *(const float4*)(p + lane * 8 + 4);
  float s  = v0.x + v0.y + v0.z + v0.w + v1.x + v1.y + v1.z + v1.w;
  float sq = v0.x*v0.x + v0.y*v0.y + v0.z*v0.z + v0.w*v0.w
           + v1.x*v1.x + v1.y*v1.y + v1.z*v1.z + v1.w*v1.w;
  s = wave_sum(s); sq = wave_sum(sq);
  float m = s * (1.f / Dsz);
  float var = sq * (1.f / Dsz) - m * m;
  float r = rsqrtf(var + 1e-5f);
  float4 w0 = *(const float4*)(w + lane * 8);
  float4 w1 = *(const float4*)(w + lane * 8 + 4);
  float4 b0 = *(const float4*)(b + lane * 8);
  float4 b1v = *(const float4*)(b + lane * 8 + 4);
  bf16x8 pk;
  pk[0] = f2bf((v0.x - m) * r * w0.x + b0.x);
  pk[1] = f2bf((v0.y - m) * r * w0.y + b0.y);
  pk[2] = f2bf((v0.z - m) * r * w0.z + b0.z);
  pk[3] = f2bf((v0.w - m) * r * w0.w + b0.w);
  pk[4] = f2bf((v1.x - m) * r * w1.x + b1v.x);
  pk[5] = f2bf((v1.y - m) * r * w1.y + b1v.y);
  pk[6] = f2bf((v1.z - m) * r * w1.z + b1v.z);
  pk[7] = f2bf((v1.w - m) * r * w1.w + b1v.w);
  *(bf16x8*)(out + (size_t)row * Dsz + lane * 8) = pk;
}

// ---- merged per-layer weight convert: qkvg(768) | o(256) | mlp1(1024) | mlp2(1024) tiles ----
__global__ __launch_bounds__(256) void wtall_kernel(
    const float* __restrict__ qw, const float* __restrict__ kw,
    const float* __restrict__ vw, const float* __restrict__ gw,
    const float* __restrict__ ow, const float* __restrict__ m1w,
    const float* __restrict__ m2w, short* __restrict__ qkvT,
    short* __restrict__ owT, short* __restrict__ m1T, short* __restrict__ m2T) {
  __shared__ float t[32][33];
  int bid = blockIdx.x;
  int tx = threadIdx.x & 31, ty = threadIdx.x >> 5;
  const float* W; short* Wt; int K, N, k0, n0, nD;
  if (bid < 768) {                       // qkvg fused -> qkvT[1536][512]
    int kx = bid & 15, ny = bid >> 4;
    int n0g = ny * 32;
    int ld;
    if (n0g < 256)       { W = qw; n0 = n0g;        ld = DKsz; }
    else if (n0g < 512)  { W = kw; n0 = n0g - 256;  ld = DKsz; }
    else if (n0g < 1024) { W = vw; n0 = n0g - 512;  ld = DVsz; }
    else                 { W = gw; n0 = n0g - 1024; ld = DVsz; }
    k0 = kx * 32; K = Dsz; N = ld; Wt = qkvT; nD = n0g;
  } else if (bid < 1024) {               // o_w [512x512] -> owT
    int idx = bid - 768;
    k0 = (idx & 15) * 32; n0 = (idx >> 4) * 32;
    W = ow; Wt = owT; K = DVsz; N = Dsz; nD = n0;
  } else if (bid < 2048) {               // mlp_w1 [512x2048] -> m1T
    int idx = bid - 1024;
    k0 = (idx & 15) * 32; n0 = (idx >> 4) * 32;
    W = m1w; Wt = m1T; K = Dsz; N = MLPsz; nD = n0;
  } else {                               // mlp_w2 [2048x512] -> m2T
    int idx = bid - 2048;
    k0 = (idx & 63) * 32; n0 = (idx >> 6) * 32;
    W = m2w; Wt = m2T; K = MLPsz; N = Dsz; nD = n0;
  }
#pragma unroll
  for (int r = 0; r < 32; r += 8)
    t[ty + r][tx] = W[(size_t)(k0 + ty + r) * N + n0 + tx];
  __syncthreads();
#pragma unroll
  for (int r = 0; r < 32; r += 8)
    Wt[(size_t)(nD + ty + r) * K + k0 + tx] = f2bf(t[tx][ty + r]);
}

// ---- bf16 MFMA GEMM, BK=64, T1 bijective XCD-chunked remap, tile 128xTN ----
// SCAT 0: C[gm][gn] = act(..)+resid, OBF selects bf16/fp32 out.
// SCAT 1 (TN=128 only): LDS-coalesced scatter -> qkPh fp16, vPh, gate fp16.
template<int ACT, int OBF, int SCAT, int TN>
__global__ __launch_bounds__(256) void mgemm_kernel(
    const short* __restrict__ A, const short* __restrict__ Bt,
    void* __restrict__ Cv, const float* __restrict__ bias,
    const float* __restrict__ resid, int N, int K) {
  constexpr int MI = (TN == 128) ? 4 : 2;      // row-frags per wave
  __shared__ short smem[128 * 64 + TN * 64];
  short* As = smem;
  short* Bs = smem + 128 * 64;
  int tid = threadIdx.x;
  int lane = tid & 63, wid = tid >> 6;
  int wrr = (TN == 128) ? (wid >> 1) : wid;
  int wcc = (TN == 128) ? (wid & 1) : 0;

  // T1 chunked remap (m204 bijective variant)
  int Ny = N / TN;
  int total = 129 * Ny;
  int q = total >> 3, r = total & 7;
  int xcd = blockIdx.x & 7, bi = blockIdx.x >> 3;
  int s = xcd * q + (xcd < r ? xcd : r);
  int w = s + bi;
  int m0 = (w / Ny) * 128, n0 = (w % Ny) * TN;

  f32x4 acc[MI][4];
#pragma unroll
  for (int i = 0; i < MI; ++i)
#pragma unroll
    for (int j = 0; j < 4; ++j) acc[i][j] = (f32x4){0.f, 0.f, 0.f, 0.f};

  int kq = lane >> 4;
  int rsel = lane & 15;

  for (int kt = 0; kt < K; kt += 64) {
#pragma unroll
    for (int i = 0; i < 4; ++i) {               // A tile: 1024 granules
      int li = i * 256 + tid;
      int row = li >> 3;
      int gsrc = (li & 7) ^ (row & 7);          // XOR-swizzled source (rule #21)
      const short* ga = A + (size_t)(m0 + row) * K + kt + gsrc * 8;
      int base = (i * 256 + wid * 64) * 8;
      __builtin_amdgcn_global_load_lds(
          (const __attribute__((address_space(1))) unsigned int*)ga,
          (__attribute__((address_space(3))) unsigned int*)&As[base], 16, 0, 0);
    }
#pragma unroll
    for (int i = 0; i < TN / 32; ++i) {         // B tile: TN*8 granules
      int li = i * 256 + tid;
      int row = li >> 3;
      int gsrc = (li & 7) ^ (row & 7);
      const short* gb = Bt + (size_t)(n0 + row) * K + kt + gsrc * 8;
      int base = (i * 256 + wid * 64) * 8;
      __builtin_amdgcn_global_load_lds(
          (const __attribute__((address_space(1))) unsigned int*)gb,
          (__attribute__((address_space(3))) unsigned int*)&Bs[base], 16, 0, 0);
    }
    __syncthreads();
#pragma unroll
    for (int s2 = 0; s2 < 2; ++s2) {
      bf16x8 af[MI], bfr[4];
#pragma unroll
      for (int i = 0; i < MI; ++i) {
        int row = wrr * (MI * 16) + i * 16 + rsel;
        int slot = (s2 * 4 + kq) ^ (row & 7);
        af[i] = *(const bf16x8*)&As[row * 64 + slot * 8];
      }
#pragma unroll
      for (int j = 0; j < 4; ++j) {
        int col = wcc * 64 + j * 16 + rsel;
        int slotB = (s2 * 4 + kq) ^ (col & 7);
        bfr[j] = *(const bf16x8*)&Bs[col * 64 + slotB * 8];
      }
#pragma unroll
      for (int i = 0; i < MI; ++i)
#pragma unroll
        for (int j = 0; j < 4; ++j)
          acc[i][j] = __builtin_amdgcn_mfma_f32_16x16x32_bf16(af[i], bfr[j], acc[i][j], 0, 0, 0);
    }
    __syncthreads();
  }

  if constexpr (SCAT == 1) {
    // ---- LDS-coalesced scatter epilogue (TN==128) ----
    // Phase 1: acc -> smem as [128 rows][128 cols] fp16
#pragma unroll
    for (int i = 0; i < MI; ++i)
#pragma unroll
      for (int j = 0; j < 4; ++j)
#pragma unroll
        for (int r2 = 0; r2 < 4; ++r2) {
          int rowL = wrr * 64 + i * 16 + (lane >> 4) * 4 + r2;
          int colL = wcc * 64 + j * 16 + rsel;
          smem[rowL * 128 + colL] =
              __builtin_bit_cast(short, __float2half(acc[i][j][r2]));
        }
    __syncthreads();
    // Phase 2: each thread stores one 64-col half-row (contiguous 128B in LDS)
    int row = tid >> 1, hsel = tid & 1;
    int gm = m0 + row;
    if (gm < Msz) {
      int bq = gm / Tsz, tq = gm - bq * Tsz;
      const short* src = &smem[row * 128 + hsel * 64];
      int gnb = n0 + hsel * 64;                  // 64-aligned global col base
      __half* qkPh = (__half*)Cv;
      if (gnb < 512) {                           // q|k: two 32-half head chunks
#pragma unroll
        for (int c0 = 0; c0 < 64; c0 += 32) {
          int gn = gnb + c0;
          int hq = (gn >> 5) & 7;
          int off = (gn & 31) | ((gn & 256) >> 3);
          __half* dst = qkPh + (((size_t)bq * 8 + hq) * Tsz + tq) * 64 + off;
#pragma unroll
          for (int k = 0; k < 4; ++k)
            ((int4*)dst)[k] = ((const int4*)(src + c0))[k];
        }
      } else if (gnb < 1024) {                   // v: one 64-half head chunk
        int hq = (gnb - 512) >> 6;
        __half* dst = qkPh + (size_t)VOFFH + (((size_t)bq * 8 + hq) * Tsz + tq) * 64;
#pragma unroll
        for (int k = 0; k < 8; ++k)
          ((int4*)dst)[k] = ((const int4*)src)[k];
      } else {                                   // gate -> gP (passed via resid)
        int hq = (gnb - 1024) >> 6;
        __half* dst = (__half*)const_cast<float*>(resid)
                      + (((size_t)bq * 8 + hq) * Tsz + tq) * 64;
#pragma unroll
        for (int k = 0; k < 8; ++k)
          ((int4*)dst)[k] = ((const int4*)src)[k];
      }
    }
  } else {
#pragma unroll
    for (int i = 0; i < MI; ++i) {
      int rbase = m0 + wrr * (MI * 16) + i * 16 + (lane >> 4) * 4;
#pragma unroll
      for (int j = 0; j < 4; ++j) {
        int gn = n0 + wcc * 64 + j * 16 + (lane & 15);
        float bv = bias ? bias[gn] : 0.f;
#pragma unroll
        for (int r2 = 0; r2 < 4; ++r2) {
          int gm = rbase + r2;
          float v = acc[i][j][r2] + bv;
          if (ACT == 1) v = gelu_fast(v);
          if (resid) v += resid[(size_t)gm * N + gn];
          if (OBF) ((short*)Cv)[(size_t)gm * N + gn] = f2bf(v);
          else     ((float*)Cv)[(size_t)gm * N + gn] = v;
        }
      }
    }
  }
}

// ---- gk merged: per row, gk1 = xn@w1 (16), then gkeP = exp(log_sigmoid(gk1@w2+b2)/16) ----
__global__ __launch_bounds__(64) void gk12_kernel(const short* __restrict__ xn,
    const float* __restrict__ w1, const float* __restrict__ w2,
    const float* __restrict__ b2, float* __restrict__ gkeP) {
  int m = blockIdx.x, lane = threadIdx.x;
  __shared__ float xr[512];
  __shared__ float y[16];
  bf16x8 v = *(const bf16x8*)(xn + (size_t)m * Dsz + lane * 8);
#pragma unroll
  for (int e = 0; e < 8; ++e) xr[lane * 8 + e] = bf2f(v[e]);
  __syncthreads();
  int c = lane & 15, q = lane >> 4;
  float acc = 0.f;
#pragma unroll 8
  for (int i = 0; i < 128; ++i) {
    int k = q * 128 + i;
    acc += xr[k] * w1[k * 16 + c];
  }
  acc += __shfl_xor(acc, 16, 64);
  acc += __shfl_xor(acc, 32, 64);
  if (lane < 16) y[c] = acc;
  __syncthreads();
  int b = m / Tsz, t = m - b * Tsz;
#pragma unroll
  for (int p = 0; p < 4; ++p) {
    int n = lane + p * 64;
    float z = b2[n];
#pragma unroll
    for (int r = 0; r < 16; ++r) z += y[r] * w2[r * 256 + n];
    float ls = (z >= 0.f) ? -log1pf(expf(-z)) : z - log1pf(expf(z));
    int hq = n >> 5;
    gkeP[(((size_t)b * 8 + hq) * Tsz + t) * 32 + (n & 31)] = expf(ls * 0.0625f);
  }
}

// ---- scan A: LDS-staged (fp16 k,v; fp32 gke) chunk-local scan from S=0 -> Ac, Bc(fp16) ----
__global__ __launch_bounds__(64) void scanA_kernel(
    const __half* __restrict__ qkPh, const float* __restrict__ gkeP,
    float* __restrict__ Ac, __half* __restrict__ Bc) {
  int gid = blockIdx.x;            // bh*NCH + c
  int bh = gid >> 5, c = gid & 31;
  int lane = threadIdx.x;
  int t0 = c * CSZ;
  int nst = min(CSZ, Tsz - t0);    // may be <= 0 for the empty tail chunk
  __shared__ __align__(16) __half s_k[CSZ * 32];
  __shared__ __align__(16) float  s_g[CSZ * 32];
  __shared__ __align__(16) __half s_v[CSZ * 64];
  const size_t rowbase = (size_t)bh * Tsz + t0;
  const __half* qksrc = qkPh + rowbase * 64;
  const __half* vsrc  = qkPh + (size_t)VOFFH + rowbase * 64;
  const float* gsrc   = gkeP + rowbase * 32;
  int nkh = nst * 4;               // k: 64B/step = 4 granules
#pragma unroll
  for (int i = 0; i < 2; ++i) {
    int gi = i * 64 + lane;
    if (gi < nkh) {
      int st = gi >> 2, gq = (gi & 3) * 8;
      __builtin_amdgcn_global_load_lds(
        (const __attribute__((address_space(1))) unsigned int*)(qksrc + (size_t)st * 64 + 32 + gq),
        (__attribute__((address_space(3))) unsigned int*)(s_k + i * 512), 16, 0, 0);
    }
  }
  int ng = nst * 8;                // gke(128B)/v(128B): 8 granules/step
#pragma unroll
  for (int i = 0; i < 3; ++i) {
    int gi = i * 64 + lane;
    if (gi < ng) {
      __builtin_amdgcn_global_load_lds(
        (const __attribute__((address_space(1))) unsigned int*)(gsrc + (size_t)gi * 4),
        (__attribute__((address_space(3))) unsigned int*)(s_g + i * 256), 16, 0, 0);
      __builtin_amdgcn_global_load_lds(
        (const __attribute__((address_space(1))) unsigned int*)(vsrc + (size_t)gi * 8),
        (__attribute__((address_space(3))) unsigned int*)(s_v + i * 512), 16, 0, 0);
    }
  }
  float S[32];
#pragma unroll
  for (int i = 0; i < 32; ++i) S[i] = 0.f;
  float ac = 1.f;
  __syncthreads();
  for (int ts = 0; ts < nst; ++ts) {
    float vv = __half2float(s_v[ts * 64 + lane]);
    const __half2* kp = (const __half2*)&s_k[ts * 32];
#pragma unroll
    for (int j = 0; j < 8; ++j) {
      float4 gg = *(const float4*)&s_g[ts * 32 + j * 4];
      float2 k01 = __half22float2(kp[2 * j]);
      float2 k23 = __half22float2(kp[2 * j + 1]);
      S[4*j+0] = S[4*j+0] * gg.x + k01.x * vv;
      S[4*j+1] = S[4*j+1] * gg.y + k01.y * vv;
      S[4*j+2] = S[4*j+2] * gg.z + k23.x * vv;
      S[4*j+3] = S[4*j+3] * gg.w + k23.y * vv;
    }
    ac *= s_g[ts * 32 + (lane & 31)];
  }
  __half* bp = Bc + ((size_t)gid * 64 + lane) * 32;
#pragma unroll
  for (int j = 0; j < 8; ++j) {
    __half2 h01 = __floats2half2_rn(S[4*j+0], S[4*j+1]);
    __half2 h23 = __floats2half2_rn(S[4*j+2], S[4*j+3]);
    *(__half2*)(bp + j * 4)     = h01;
    *(__half2*)(bp + j * 4 + 2) = h23;
  }
  if (lane < 32) Ac[(size_t)gid * 32 + lane] = ac;
}

// ---- scan B: per (b,h) combine chunks; Bc slot c := S_init(c) (in place, fp16) ----
__global__ __launch_bounds__(64) void scanB_kernel(
    const float* __restrict__ Ac, __half* __restrict__ Bc) {
  int bh = blockIdx.x;
  int lane = threadIdx.x;
  float cur[32];
#pragma unroll
  for (int i = 0; i < 32; ++i) cur[i] = 0.f;
  __shared__ float sA[32];
  for (int c = 0; c < NCH; ++c) {
    size_t gid = (size_t)bh * NCH + c;
    __half* bp = Bc + (gid * 64 + lane) * 32;
    __syncthreads();
    if (lane < 32) sA[lane] = Ac[gid * 32 + lane];
    __syncthreads();
    float tb[32];
#pragma unroll
    for (int j = 0; j < 8; ++j) {
      float2 t01 = __half22float2(*(const __half2*)(bp + j * 4));
      float2 t23 = __half22float2(*(const __half2*)(bp + j * 4 + 2));
      tb[4*j+0] = t01.x; tb[4*j+1] = t01.y; tb[4*j+2] = t23.x; tb[4*j+3] = t23.y;
    }
#pragma unroll
    for (int j = 0; j < 8; ++j) {
      *(__half2*)(bp + j * 4)     = __floats2half2_rn(cur[4*j+0], cur[4*j+1]);
      *(__half2*)(bp + j * 4 + 2) = __floats2half2_rn(cur[4*j+2], cur[4*j+3]);
    }
#pragma unroll
    for (int i = 0; i < 32; ++i)
      cur[i] = sA[i] * cur[i] + tb[i];
  }
}

// ---- scan C: LDS-staged (fp16 q,k,v,gate; fp32 gke) re-scan from fp16 S_init, emit att ----
__global__ __launch_bounds__(64) void scanC_kernel(
    const __half* __restrict__ qkPh, const __half* __restrict__ gP,
    const float* __restrict__ gkeP, const float* __restrict__ gnw,
    const __half* __restrict__ Bc, short* __restrict__ att) {
  int gid = blockIdx.x;
  int bh = gid >> 5, c = gid & 31;
  int b = bh >> 3, hh = bh & 7;
  int lane = threadIdx.x;
  int t0 = c * CSZ;
  int nst = min(CSZ, Tsz - t0);
  __shared__ __align__(16) __half s_qk[CSZ * 64];
  __shared__ __align__(16) float  s_g[CSZ * 32];
  __shared__ __align__(16) __half s_v[CSZ * 64];
  __shared__ __align__(16) __half s_gt[CSZ * 64];
  const size_t rowbase = (size_t)bh * Tsz + t0;
  const __half* qksrc = qkPh + rowbase * 64;
  const __half* vsrc  = qkPh + (size_t)VOFFH + rowbase * 64;
  const float* gsrc   = gkeP + rowbase * 32;
  const __half* gtsrc = gP + rowbase * 64;
  int ng = nst * 8;                // 8 granules/step for qk(128B), v, gt, g
#pragma unroll
  for (int i = 0; i < 3; ++i) {
    int gi = i * 64 + lane;
    if (gi < ng) {
      __builtin_amdgcn_global_load_lds(
        (const __attribute__((address_space(1))) unsigned int*)(qksrc + (size_t)gi * 8),
        (__attribute__((address_space(3))) unsigned int*)(s_qk + i * 512), 16, 0, 0);
      __builtin_amdgcn_global_load_lds(
        (const __attribute__((address_space(1))) unsigned int*)(vsrc + (size_t)gi * 8),
        (__attribute__((address_space(3))) unsigned int*)(s_v + i * 512), 16, 0, 0);
      __builtin_amdgcn_global_load_lds(
        (const __attribute__((address_space(1))) unsigned int*)(gsrc + (size_t)gi * 4),
        (__attribute__((address_space(3))) unsigned int*)(s_g + i * 256), 16, 0, 0);
      __builtin_amdgcn_global_load_lds(
        (const __attribute__((address_space(1))) unsigned int*)(gtsrc + (size_t)gi * 8),
        (__attribute__((address_space(3))) unsigned int*)(s_gt + i * 512), 16, 0, 0);
    }
  }
  float S[32];
  const __half* sp = Bc + ((size_t)gid * 64 + lane) * 32;
#pragma unroll
  for (int j = 0; j < 8; ++j) {
    float2 s01 = __half22float2(*(const __half2*)(sp + j * 4));
    float2 s23 = __half22float2(*(const __half2*)(sp + j * 4 + 2));
    S[4*j+0] = s01.x; S[4*j+1] = s01.y; S[4*j+2] = s23.x; S[4*j+3] = s23.y;
  }
  float gn = gnw[lane];
  __syncthreads();
  for (int ts = 0; ts < nst; ++ts) {
    float vv = __half2float(s_v[ts * 64 + lane]);
    float gv = __half2float(s_gt[ts * 64 + lane]);
    const __half2* qp = (const __half2*)&s_qk[ts * 64];
    const __half2* kp = qp + 16;
    float o0 = 0.f, o1 = 0.f, o2 = 0.f, o3 = 0.f;
#pragma unroll
    for (int j = 0; j < 8; ++j) {
      float4 gg = *(const float4*)&s_g[ts * 32 + j * 4];
      float2 q01 = __half22float2(qp[2 * j]);
      float2 q23 = __half22float2(qp[2 * j + 1]);
      float2 k01 = __half22float2(kp[2 * j]);
      float2 k23 = __half22float2(kp[2 * j + 1]);
      S[4*j+0] = S[4*j+0] * gg.x + k01.x * vv;  o0 += q01.x * S[4*j+0];
      S[4*j+1] = S[4*j+1] * gg.y + k01.y * vv;  o1 += q01.y * S[4*j+1];
      S[4*j+2] = S[4*j+2] * gg.z + k23.x * vv;  o2 += q23.x * S[4*j+2];
      S[4*j+3] = S[4*j+3] * gg.w + k23.y * vv;  o3 += q23.y * S[4*j+3];
    }
    float o = ((o0 + o1) + (o2 + o3)) * 0.17677669529663689f;   // 32^-0.5
    float ss = wave_sum(o * o);
    float r = rsqrtf(ss * (1.f / 64.f) + 1e-5f);
    float sig = 1.f / (1.f + expf(-gv));
    att[((size_t)b * Tsz + t0 + ts) * DVsz + hh * HVsz + lane] = f2bf(o * r * gn * gv * sig);
  }
}

// ---- final head ----
__global__ __launch_bounds__(64) void head_kernel(
    const float* __restrict__ h, const float* __restrict__ hw,
    const float* __restrict__ hb, float* __restrict__ out) {
  int b = blockIdx.x, lane = threadIdx.x;
  const float* p = h + ((size_t)b * Tsz + Ssz) * Dsz;
  float p0 = 0.f, p1 = 0.f, p2 = 0.f;
#pragma unroll
  for (int j = 0; j < 8; ++j) {
    int d = lane + j * 64;
    float hv = p[d];
    p0 += hv * hw[d * 3 + 0];
    p1 += hv * hw[d * 3 + 1];
    p2 += hv * hw[d * 3 + 2];
  }
  p0 = wave_sum(p0); p1 = wave_sum(p1); p2 = wave_sum(p2);
  if (lane == 0) {
    out[b * 3 + 0] = p0 + hb[0];
    out[b * 3 + 1] = p1 + hb[1];
    out[b * 3 + 2] = p2 + hb[2];
  }
}

extern "C" void kernel_launch(void* const* d_in, const int* in_sizes, int n_in,
                              void* d_out, int out_size, void* d_ws, size_t ws_size,
                              hipStream_t stream) {
  const float* x       = (const float*)d_in[0];
  const float* bin_l1  = (const float*)d_in[1];
  const float* bin_b1  = (const float*)d_in[2];
  const float* bin_l2  = (const float*)d_in[3];
  const float* bin_b2  = (const float*)d_in[4];
  const float* bin_y1  = (const float*)d_in[5];
  const float* bin_y2  = (const float*)d_in[6];
  const float* emb_w   = (const float*)d_in[7];
  const float* emb_b   = (const float*)d_in[8];
  const float* cls     = (const float*)d_in[9];
  const float* ln1_w   = (const float*)d_in[10];
  const float* ln1_b   = (const float*)d_in[11];
  const float* q_w     = (const float*)d_in[12];
  const float* k_w     = (const float*)d_in[13];
  const float* v_w     = (const float*)d_in[14];
  const float* g_w     = (const float*)d_in[15];
  const float* gk_w1   = (const float*)d_in[16];
  const float* gk_w2   = (const float*)d_in[17];
  const float* gk_b2   = (const float*)d_in[18];
  const float* gnorm_w = (const float*)d_in[19];
  const float* o_w     = (const float*)d_in[20];
  const float* ln2_w   = (const float*)d_in[21];
  const float* ln2_b   = (const float*)d_in[22];
  const float* mlp_w1  = (const float*)d_in[23];
  const float* mlp_b1  = (const float*)d_in[24];
  const float* mlp_w2  = (const float*)d_in[25];
  const float* mlp_b2  = (const float*)d_in[26];
  const float* head_w  = (const float*)d_in[27];
  const float* head_b  = (const float*)d_in[28];
  float* out = (float*)d_out;

  // ---- workspace layout (~163 MB; Bc lives in the dead tail of qkP region) ----
  char* wptr = (char*)d_ws;
  auto alloc = [&](size_t bytes) { char* p = wptr; wptr += (bytes + 255) & ~(size_t)255; return p; };
  float* pos  = (float*)alloc((size_t)Tsz * Dsz * 4);
  float* h    = (float*)alloc((size_t)Mpad * Dsz * 4);
  short* xn   = (short*)alloc((size_t)Mpad * Dsz * 2);      // LN out; aliased as att
  float* qkP  = (float*)alloc((size_t)Mpad * MLPsz * 2);    // qkPh|vPh|Bc ; also xbT / mid
  float* gkeP = (float*)alloc((size_t)256 * Tsz * 32 * 4);
  __half* gP  = (__half*)alloc((size_t)256 * Tsz * 64 * 2);
  float* mt   = (float*)alloc((size_t)Bsz * Fsz * 4);
  float* rst  = (float*)alloc((size_t)Bsz * Fsz * 4);
  float* Ac   = (float*)alloc((size_t)Bsz * Hh * NCH * 32 * 4);
  short* wtr  = (short*)alloc((size_t)3145728 * 2);         // per-layer bf16 weights
  float* xbT  = qkP;             // [40][Mpad] fp32, dead before qkv GEMM
  short* mid  = (short*)qkP;     // MLP mid bf16, aliases qkPh/vPh/Bc (dead by MLP)
  short* att  = xn;              // scan output aliases xn (dead after gk12)
  __half* qkPh = (__half*)qkP;   // fp16 q|k rows; vPh = qkPh + VOFFH
  __half* Bc  = qkPh + (size_t)2 * VOFFH;   // fp16 chunk states, 33.5 MB in dead tail

  short* qkvT = wtr;                          // [1536][512]
  short* owT  = qkvT + 786432;
  short* m1T  = owT + 262144;
  short* m2T  = m1T + 1048576;

  // ---- pre ----
  hipLaunchKernelGGL(pos_kernel, dim3((Tsz * Dsz + 255) / 256), dim3(256), 0, stream, pos);
  hipLaunchKernelGGL(tstat_kernel, dim3(Bsz * Fsz), dim3(64), 0, stream, x, mt, rst);
  hipLaunchKernelGGL(binorm_kernel, dim3(Mpad), dim3(64), 0, stream,
                     x, bin_l1, bin_b1, bin_l2, bin_b2, bin_y1, bin_y2, mt, rst, xbT);
  hipLaunchKernelGGL(embgemm_kernel, dim3(258, 8), dim3(256), 0, stream,
                     xbT, emb_w, emb_b, cls, pos, h);

  dim3 blk256(256);
  for (int l = 0; l < Lnum; ++l) {
    hipLaunchKernelGGL(wtall_kernel, dim3(3072), blk256, 0, stream,
                       q_w + (size_t)l*Dsz*DKsz, k_w + (size_t)l*Dsz*DKsz,
                       v_w + (size_t)l*Dsz*DVsz, g_w + (size_t)l*Dsz*DVsz,
                       o_w + (size_t)l*DVsz*Dsz, mlp_w1 + (size_t)l*Dsz*MLPsz,
                       mlp_w2 + (size_t)l*MLPsz*Dsz, qkvT, owT, m1T, m2T);

    const float* lw1 = ln1_w + l * Dsz;  const float* lb1 = ln1_b + l * Dsz;
    const float* g1w = gk_w1 + (size_t)l * Dsz * 16;
    const float* g2w = gk_w2 + (size_t)l * 16 * DKsz;
    const float* g2b = gk_b2 + (size_t)l * DKsz;
    const float* gnw = gnorm_w + l * HVsz;
    const float* lw2 = ln2_w + l * Dsz;  const float* lb2 = ln2_b + l * Dsz;
    const float* m1b = mlp_b1 + (size_t)l * MLPsz;
    const float* m2b = mlp_b2 + (size_t)l * Dsz;

    hipLaunchKernelGGL(ln_kernel, dim3(Msz), dim3(64), 0, stream, h, lw1, lb1, xn);

    // packed q|k|v|g projection (N=1536, TN=128) with LDS-coalesced fp16 scatter
    hipLaunchKernelGGL((mgemm_kernel<0,0,1,128>), dim3(129 * 12), blk256, 0, stream,
                       xn, qkvT, (void*)qkPh, (const float*)nullptr, (const float*)gP, QKVG, Dsz);
    // merged gk low-rank path (one launch)
    hipLaunchKernelGGL(gk12_kernel, dim3(Msz), dim3(64), 0, stream, xn, g1w, g2w, g2b, gkeP);

    // chunk-parallel GLA scan (NCH=32, fp16 operands+state buffers / fp32 recurrence)
    hipLaunchKernelGGL(scanA_kernel, dim3(Bsz * Hh * NCH), dim3(64), 0, stream,
                       qkPh, gkeP, Ac, Bc);
    hipLaunchKernelGGL(scanB_kernel, dim3(Bsz * Hh), dim3(64), 0, stream, Ac, Bc);
    hipLaunchKernelGGL(scanC_kernel, dim3(Bsz * Hh * NCH), dim3(64), 0, stream,
                       qkPh, gP, gkeP, gnw, Bc, att);

    // h = h + att @ o_w   (N=512, TN=64 -> 1032 blocks)
    hipLaunchKernelGGL((mgemm_kernel<0,0,0,64>), dim3(129 * 8), blk256, 0, stream,
                       att, owT, (void*)h, (const float*)nullptr, h, Dsz, DVsz);

    hipLaunchKernelGGL(ln_kernel, dim3(Msz), dim3(64), 0, stream, h, lw2, lb2, xn);
    // mid = gelu_fast(xn @ w1 + b1)   (bf16 out, TN=128)
    hipLaunchKernelGGL((mgemm_kernel<1,1,0,128>), dim3(129 * 16), blk256, 0, stream,
                       xn, m1T, (void*)mid, m1b, (const float*)nullptr, MLPsz, Dsz);
    // h = h + mid @ w2 + b2   (N=512, TN=64 -> 1032 blocks)
    hipLaunchKernelGGL((mgemm_kernel<0,0,0,64>), dim3(129 * 8), blk256, 0, stream,
                       mid, m2T, (void*)h, m2b, h, Dsz, MLPsz);
  }

  hipLaunchKernelGGL(head_kernel, dim3(Bsz), dim3(64), 0, stream, h, head_w, head_b, out);
}

// Round 18
// 1559.594 us; speedup vs baseline: 1.0119x; 1.0119x over previous
//
#include <hip/hip_runtime.h>
#include <hip/hip_bf16.h>
#include <hip/hip_fp16.h>
#include <math.h>

// ---- problem constants ----
#define Bsz   32
#define Ssz   512
#define Fsz   40
#define Dsz   512
#define Hh    8
#define Lnum  4
#define Tsz   513           // S + 1 (cls token)
#define DKsz  256
#define DVsz  512
#define HKsz  32
#define HVsz  64
#define Msz   (Bsz*Tsz)     // 16416 rows
#define Mpad  16512         // 129*128, padded row count for 128-tiles
#define MLPsz 2048
#define NCH   32            // scan chunks per (b,h)
#define CSZ   17            // chunk size (last real chunk = 3; chunk 31 empty)
#define QKVG  1536          // packed q|k|v|g GEMM width
#define VOFFH 8404992       // half offset of vP within qkPh block (256*513*64)

typedef __attribute__((ext_vector_type(4))) float f32x4;
typedef __attribute__((ext_vector_type(8))) short bf16x8;

__device__ __forceinline__ float bf2f(short s) {
  unsigned int u = ((unsigned int)(unsigned short)s) << 16;
  return __builtin_bit_cast(float, u);
}
__device__ __forceinline__ short f2bf(float f) {
  __hip_bfloat16 b = __float2bfloat16(f);
  return __builtin_bit_cast(short, b);
}

__device__ __forceinline__ float wave_sum(float v) {
#pragma unroll
  for (int off = 32; off > 0; off >>= 1) v += __shfl_xor(v, off, 64);
  return v;
}

// ---- positional encoding table (T x D) ----
__global__ void pos_kernel(float* __restrict__ pos) {
  int idx = blockIdx.x * 256 + threadIdx.x;
  if (idx >= Tsz * Dsz) return;
  int t = idx / Dsz, d = idx % Dsz;
  float e = (float)(2 * (d >> 1)) / (float)Dsz;
  float den = powf(10000.f, e);
  float a = (float)t / den;
  pos[idx] = (d & 1) ? cosf(a) : sinf(a);
}

// ---- BiN temporal stats: per (b,f) mean + 1/std over S (ddof=1) ----
__global__ void tstat_kernel(const float* __restrict__ x,
                             float* __restrict__ mt, float* __restrict__ rst) {
  int bf = blockIdx.x;
  int b = bf / Fsz, f = bf % Fsz;
  int lane = threadIdx.x;
  const float* xp = x + (size_t)b * Ssz * Fsz + f;
  float s = 0.f, sq = 0.f;
  for (int i = lane; i < Ssz; i += 64) {
    float v = xp[(size_t)i * Fsz];
    s += v; sq += v * v;
  }
  s = wave_sum(s); sq = wave_sum(sq);
  if (lane == 0) {
    float m = s / (float)Ssz;
    float var = (sq - (float)Ssz * m * m) / (float)(Ssz - 1);
    float st = sqrtf(fmaxf(var, 0.f));
    if (st < 1e-4f) st = 1.f;
    mt[bf] = m;
    rst[bf] = 1.f / st;
  }
}

// ---- BiN both norms -> xbT[f][row] (transposed, fp32); zero cls/pad rows ----
__global__ __launch_bounds__(64) void binorm_kernel(
    const float* __restrict__ x, const float* __restrict__ l1,
    const float* __restrict__ b1, const float* __restrict__ l2,
    const float* __restrict__ b2, const float* __restrict__ y1p,
    const float* __restrict__ y2p, const float* __restrict__ mt,
    const float* __restrict__ rst, float* __restrict__ xbT) {
  int row = blockIdx.x;              // 0..Mpad-1
  int lane = threadIdx.x;
  int b = row / Tsz, t = row % Tsz;
  bool valid = (row < Msz) && (t < Ssz);
  if (!valid) {
    if (lane < Fsz) xbT[(size_t)lane * Mpad + row] = 0.f;
    return;
  }
  float xv = 0.f;
  const float* xp = x + ((size_t)b * Ssz + t) * Fsz;
  if (lane < Fsz) xv = xp[lane];
  float s  = wave_sum(lane < Fsz ? xv : 0.f);
  float sq = wave_sum(lane < Fsz ? xv * xv : 0.f);
  float m = s / (float)Fsz;
  float var = (sq - (float)Fsz * m * m) / (float)(Fsz - 1);
  float sf = sqrtf(fmaxf(var, 0.f));
  if (sf < 1e-4f) sf = 1.f;
  if (lane < Fsz) {
    float y1 = y1p[0], y2 = y2p[0];
    float z1 = (xv - m) / sf;
    float X1 = l1[t] * z1 + b1[t];
    int bf = b * Fsz + lane;
    float z2 = (xv - mt[bf]) * rst[bf];
    float X2 = l2[lane] * z2 + b2[lane];
    xbT[(size_t)lane * Mpad + row] = y1 * X1 + y2 * X2;
  }
}

// ---- embed GEMM: h[row][d] = xbT^T @ emb_w + emb_b + pos (cls rows special) ----
__global__ __launch_bounds__(256, 4) void embgemm_kernel(
    const float* __restrict__ xbT, const float* __restrict__ emb_w,
    const float* __restrict__ emb_b, const float* __restrict__ cls,
    const float* __restrict__ pos, float* __restrict__ h) {
  __shared__ float as[Fsz][64];
  __shared__ float bs[Fsz][64];
  int tid = threadIdx.x, tx = tid & 15, ty = tid >> 4;
  int r0 = blockIdx.x * 64, c0 = blockIdx.y * 64;
  for (int idx = tid; idx < Fsz * 64; idx += 256) {
    int f = idx >> 6, r = idx & 63;
    as[f][r] = xbT[(size_t)f * Mpad + r0 + r];
    bs[f][r] = emb_w[f * Dsz + c0 + r];
  }
  __syncthreads();
  float acc[4][4] = {};
#pragma unroll 5
  for (int f = 0; f < Fsz; ++f) {
    float4 a = *(const float4*)&as[f][ty * 4];
    float4 bv = *(const float4*)&bs[f][tx * 4];
    float av[4] = {a.x, a.y, a.z, a.w};
    float bw[4] = {bv.x, bv.y, bv.z, bv.w};
#pragma unroll
    for (int i = 0; i < 4; ++i)
#pragma unroll
      for (int j = 0; j < 4; ++j) acc[i][j] += av[i] * bw[j];
  }
#pragma unroll
  for (int i = 0; i < 4; ++i) {
    int gm = r0 + ty * 4 + i;
    int t = gm % Tsz;
    const float* pp = pos + (size_t)t * Dsz;
    bool iscls = (t == Ssz);
    int gn = c0 + tx * 4;
#pragma unroll
    for (int j = 0; j < 4; ++j) {
      float v = iscls ? (cls[gn + j] + pp[gn + j])
                      : (acc[i][j] + emb_b[gn + j] + pp[gn + j]);
      h[(size_t)gm * Dsz + gn + j] = v;
    }
  }
}

// ---- LayerNorm over D=512 (fp32 in, bf16 out) ----
__global__ __launch_bounds__(64) void ln_kernel(
    const float* __restrict__ in, const float* __restrict__ w,
    const float* __restrict__ b, short* __restrict__ out) {
  int row = blockIdx.x, lane = threadIdx.x;
  const float* p = in + (size_t)row * Dsz;
  float4 v0 = *(const float4*)(p + lane * 8);
  float4 v1 = *(const float4*)(p + lane * 8 + 4);
  float s  = v0.x + v0.y + v0.z + v0.w + v1.x + v1.y + v1.z + v1.w;
  float sq = v0.x*v0.x + v0.y*v0.y + v0.z*v0.z + v0.w*v0.w
           + v1.x*v1.x + v1.y*v1.y + v1.z*v1.z + v1.w*v1.w;
  s = wave_sum(s); sq = wave_sum(sq);
  float m = s * (1.f / Dsz);
  float var = sq * (1.f / Dsz) - m * m;
  float r = rsqrtf(var + 1e-5f);
  float4 w0 = *(const float4*)(w + lane * 8);
  float4 w1 = *(const float4*)(w + lane * 8 + 4);
  float4 b0 = *(const float4*)(b + lane * 8);
  float4 b1v = *(const float4*)(b + lane * 8 + 4);
  bf16x8 pk;
  pk[0] = f2bf((v0.x - m) * r * w0.x + b0.x);
  pk[1] = f2bf((v0.y - m) * r * w0.y + b0.y);
  pk[2] = f2bf((v0.z - m) * r * w0.z + b0.z);
  pk[3] = f2bf((v0.w - m) * r * w0.w + b0.w);
  pk[4] = f2bf((v1.x - m) * r * w1.x + b1v.x);
  pk[5] = f2bf((v1.y - m) * r * w1.y + b1v.y);
  pk[6] = f2bf((v1.z - m) * r * w1.z + b1v.z);
  pk[7] = f2bf((v1.w - m) * r * w1.w + b1v.w);
  *(bf16x8*)(out + (size_t)row * Dsz + lane * 8) = pk;
}

// ---- merged per-layer weight convert: qkvg(768) | o(256) | mlp1(1024) | mlp2(1024) tiles ----
__global__ __launch_bounds__(256) void wtall_kernel(
    const float* __restrict__ qw, const float* __restrict__ kw,
    const float* __restrict__ vw, const float* __restrict__ gw,
    const float* __restrict__ ow, const float* __restrict__ m1w,
    const float* __restrict__ m2w, short* __restrict__ qkvT,
    short* __restrict__ owT, short* __restrict__ m1T, short* __restrict__ m2T) {
  __shared__ float t[32][33];
  int bid = blockIdx.x;
  int tx = threadIdx.x & 31, ty = threadIdx.x >> 5;
  const float* W; short* Wt; int K, N, k0, n0, nD;
  if (bid < 768) {                       // qkvg fused -> qkvT[1536][512]
    int kx = bid & 15, ny = bid >> 4;
    int n0g = ny * 32;
    int ld;
    if (n0g < 256)       { W = qw; n0 = n0g;        ld = DKsz; }
    else if (n0g < 512)  { W = kw; n0 = n0g - 256;  ld = DKsz; }
    else if (n0g < 1024) { W = vw; n0 = n0g - 512;  ld = DVsz; }
    else                 { W = gw; n0 = n0g - 1024; ld = DVsz; }
    k0 = kx * 32; K = Dsz; N = ld; Wt = qkvT; nD = n0g;
  } else if (bid < 1024) {               // o_w [512x512] -> owT
    int idx = bid - 768;
    k0 = (idx & 15) * 32; n0 = (idx >> 4) * 32;
    W = ow; Wt = owT; K = DVsz; N = Dsz; nD = n0;
  } else if (bid < 2048) {               // mlp_w1 [512x2048] -> m1T
    int idx = bid - 1024;
    k0 = (idx & 15) * 32; n0 = (idx >> 4) * 32;
    W = m1w; Wt = m1T; K = Dsz; N = MLPsz; nD = n0;
  } else {                               // mlp_w2 [2048x512] -> m2T
    int idx = bid - 2048;
    k0 = (idx & 63) * 32; n0 = (idx >> 6) * 32;
    W = m2w; Wt = m2T; K = MLPsz; N = Dsz; nD = n0;
  }
#pragma unroll
  for (int r = 0; r < 32; r += 8)
    t[ty + r][tx] = W[(size_t)(k0 + ty + r) * N + n0 + tx];
  __syncthreads();
#pragma unroll
  for (int r = 0; r < 32; r += 8)
    Wt[(size_t)(nD + ty + r) * K + k0 + tx] = f2bf(t[tx][ty + r]);
}

// ---- bf16 MFMA GEMM, BK=64, T1 bijective XCD-chunked remap, tile 128xTN ----
// SCAT 0: C[gm][gn] = act(..)+resid, OBF selects bf16/fp32 out.
// SCAT 1 (TN=128 only): LDS-coalesced scatter -> qkPh fp16, vPh, gate fp16.
template<int ACT, int OBF, int SCAT, int TN>
__global__ __launch_bounds__(256) void mgemm_kernel(
    const short* __restrict__ A, const short* __restrict__ Bt,
    void* __restrict__ Cv, const float* __restrict__ bias,
    const float* __restrict__ resid, int N, int K) {
  constexpr int MI = (TN == 128) ? 4 : 2;      // row-frags per wave
  __shared__ short smem[128 * 64 + TN * 64];
  short* As = smem;
  short* Bs = smem + 128 * 64;
  int tid = threadIdx.x;
  int lane = tid & 63, wid = tid >> 6;
  int wrr = (TN == 128) ? (wid >> 1) : wid;
  int wcc = (TN == 128) ? (wid & 1) : 0;

  // T1 chunked remap (m204 bijective variant)
  int Ny = N / TN;
  int total = 129 * Ny;
  int q = total >> 3, r = total & 7;
  int xcd = blockIdx.x & 7, bi = blockIdx.x >> 3;
  int s = xcd * q + (xcd < r ? xcd : r);
  int w = s + bi;
  int m0 = (w / Ny) * 128, n0 = (w % Ny) * TN;

  f32x4 acc[MI][4];
#pragma unroll
  for (int i = 0; i < MI; ++i)
#pragma unroll
    for (int j = 0; j < 4; ++j) acc[i][j] = (f32x4){0.f, 0.f, 0.f, 0.f};

  int kq = lane >> 4;
  int rsel = lane & 15;

  for (int kt = 0; kt < K; kt += 64) {
#pragma unroll
    for (int i = 0; i < 4; ++i) {               // A tile: 1024 granules
      int li = i * 256 + tid;
      int row = li >> 3;
      int gsrc = (li & 7) ^ (row & 7);          // XOR-swizzled source (rule #21)
      const short* ga = A + (size_t)(m0 + row) * K + kt + gsrc * 8;
      int base = (i * 256 + wid * 64) * 8;
      __builtin_amdgcn_global_load_lds(
          (const __attribute__((address_space(1))) unsigned int*)ga,
          (__attribute__((address_space(3))) unsigned int*)&As[base], 16, 0, 0);
    }
#pragma unroll
    for (int i = 0; i < TN / 32; ++i) {         // B tile: TN*8 granules
      int li = i * 256 + tid;
      int row = li >> 3;
      int gsrc = (li & 7) ^ (row & 7);
      const short* gb = Bt + (size_t)(n0 + row) * K + kt + gsrc * 8;
      int base = (i * 256 + wid * 64) * 8;
      __builtin_amdgcn_global_load_lds(
          (const __attribute__((address_space(1))) unsigned int*)gb,
          (__attribute__((address_space(3))) unsigned int*)&Bs[base], 16, 0, 0);
    }
    __syncthreads();
#pragma unroll
    for (int s2 = 0; s2 < 2; ++s2) {
      bf16x8 af[MI], bfr[4];
#pragma unroll
      for (int i = 0; i < MI; ++i) {
        int row = wrr * (MI * 16) + i * 16 + rsel;
        int slot = (s2 * 4 + kq) ^ (row & 7);
        af[i] = *(const bf16x8*)&As[row * 64 + slot * 8];
      }
#pragma unroll
      for (int j = 0; j < 4; ++j) {
        int col = wcc * 64 + j * 16 + rsel;
        int slotB = (s2 * 4 + kq) ^ (col & 7);
        bfr[j] = *(const bf16x8*)&Bs[col * 64 + slotB * 8];
      }
#pragma unroll
      for (int i = 0; i < MI; ++i)
#pragma unroll
        for (int j = 0; j < 4; ++j)
          acc[i][j] = __builtin_amdgcn_mfma_f32_16x16x32_bf16(af[i], bfr[j], acc[i][j], 0, 0, 0);
    }
    __syncthreads();
  }

  if constexpr (SCAT == 1) {
    // ---- LDS-coalesced scatter epilogue (TN==128) ----
    // Phase 1: acc -> smem as [128 rows][128 cols] fp16
#pragma unroll
    for (int i = 0; i < MI; ++i)
#pragma unroll
      for (int j = 0; j < 4; ++j)
#pragma unroll
        for (int r2 = 0; r2 < 4; ++r2) {
          int rowL = wrr * 64 + i * 16 + (lane >> 4) * 4 + r2;
          int colL = wcc * 64 + j * 16 + rsel;
          smem[rowL * 128 + colL] =
              __builtin_bit_cast(short, __float2half(acc[i][j][r2]));
        }
    __syncthreads();
    // Phase 2: each thread stores one 64-col half-row (contiguous 128B in LDS)
    int row = tid >> 1, hsel = tid & 1;
    int gm = m0 + row;
    if (gm < Msz) {
      int bq = gm / Tsz, tq = gm - bq * Tsz;
      const short* src = &smem[row * 128 + hsel * 64];
      int gnb = n0 + hsel * 64;                  // 64-aligned global col base
      __half* qkPh = (__half*)Cv;
      if (gnb < 512) {                           // q|k: two 32-half head chunks
#pragma unroll
        for (int c0 = 0; c0 < 64; c0 += 32) {
          int gn = gnb + c0;
          int hq = (gn >> 5) & 7;
          int off = (gn & 31) | ((gn & 256) >> 3);
          __half* dst = qkPh + (((size_t)bq * 8 + hq) * Tsz + tq) * 64 + off;
#pragma unroll
          for (int k = 0; k < 4; ++k)
            ((int4*)dst)[k] = ((const int4*)(src + c0))[k];
        }
      } else if (gnb < 1024) {                   // v: one 64-half head chunk
        int hq = (gnb - 512) >> 6;
        __half* dst = qkPh + (size_t)VOFFH + (((size_t)bq * 8 + hq) * Tsz + tq) * 64;
#pragma unroll
        for (int k = 0; k < 8; ++k)
          ((int4*)dst)[k] = ((const int4*)src)[k];
      } else {                                   // gate -> gP (passed via resid)
        int hq = (gnb - 1024) >> 6;
        __half* dst = (__half*)const_cast<float*>(resid)
                      + (((size_t)bq * 8 + hq) * Tsz + tq) * 64;
#pragma unroll
        for (int k = 0; k < 8; ++k)
          ((int4*)dst)[k] = ((const int4*)src)[k];
      }
    }
  } else {
#pragma unroll
    for (int i = 0; i < MI; ++i) {
      int rbase = m0 + wrr * (MI * 16) + i * 16 + (lane >> 4) * 4;
#pragma unroll
      for (int j = 0; j < 4; ++j) {
        int gn = n0 + wcc * 64 + j * 16 + (lane & 15);
        float bv = bias ? bias[gn] : 0.f;
#pragma unroll
        for (int r2 = 0; r2 < 4; ++r2) {
          int gm = rbase + r2;
          float v = acc[i][j][r2] + bv;
          if (ACT == 1) v = 0.5f * v * (1.f + erff(v * 0.70710678118654752f));
          if (resid) v += resid[(size_t)gm * N + gn];
          if (OBF) ((short*)Cv)[(size_t)gm * N + gn] = f2bf(v);
          else     ((float*)Cv)[(size_t)gm * N + gn] = v;
        }
      }
    }
  }
}

// ---- gk merged: per row, gk1 = xn@w1 (16), then gkeP = exp(log_sigmoid(gk1@w2+b2)/16) ----
__global__ __launch_bounds__(64) void gk12_kernel(const short* __restrict__ xn,
    const float* __restrict__ w1, const float* __restrict__ w2,
    const float* __restrict__ b2, float* __restrict__ gkeP) {
  int m = blockIdx.x, lane = threadIdx.x;
  __shared__ float xr[512];
  __shared__ float y[16];
  bf16x8 v = *(const bf16x8*)(xn + (size_t)m * Dsz + lane * 8);
#pragma unroll
  for (int e = 0; e < 8; ++e) xr[lane * 8 + e] = bf2f(v[e]);
  __syncthreads();
  int c = lane & 15, q = lane >> 4;
  float acc = 0.f;
#pragma unroll 8
  for (int i = 0; i < 128; ++i) {
    int k = q * 128 + i;
    acc += xr[k] * w1[k * 16 + c];
  }
  acc += __shfl_xor(acc, 16, 64);
  acc += __shfl_xor(acc, 32, 64);
  if (lane < 16) y[c] = acc;
  __syncthreads();
  int b = m / Tsz, t = m - b * Tsz;
#pragma unroll
  for (int p = 0; p < 4; ++p) {
    int n = lane + p * 64;
    float z = b2[n];
#pragma unroll
    for (int r = 0; r < 16; ++r) z += y[r] * w2[r * 256 + n];
    float ls = (z >= 0.f) ? -log1pf(expf(-z)) : z - log1pf(expf(z));
    int hq = n >> 5;
    gkeP[(((size_t)b * 8 + hq) * Tsz + t) * 32 + (n & 31)] = expf(ls * 0.0625f);
  }
}

// ---- scan A: LDS-staged (fp16 k,v; fp32 gke) chunk-local scan from S=0 -> Ac, Bc(fp16) ----
__global__ __launch_bounds__(64) void scanA_kernel(
    const __half* __restrict__ qkPh, const float* __restrict__ gkeP,
    float* __restrict__ Ac, __half* __restrict__ Bc) {
  int gid = blockIdx.x;            // bh*NCH + c
  int bh = gid >> 5, c = gid & 31;
  int lane = threadIdx.x;
  int t0 = c * CSZ;
  int nst = min(CSZ, Tsz - t0);    // may be <= 0 for the empty tail chunk
  __shared__ __align__(16) __half s_k[CSZ * 32];
  __shared__ __align__(16) float  s_g[CSZ * 32];
  __shared__ __align__(16) __half s_v[CSZ * 64];
  const size_t rowbase = (size_t)bh * Tsz + t0;
  const __half* qksrc = qkPh + rowbase * 64;
  const __half* vsrc  = qkPh + (size_t)VOFFH + rowbase * 64;
  const float* gsrc   = gkeP + rowbase * 32;
  int nkh = nst * 4;               // k: 64B/step = 4 granules
#pragma unroll
  for (int i = 0; i < 2; ++i) {
    int gi = i * 64 + lane;
    if (gi < nkh) {
      int st = gi >> 2, gq = (gi & 3) * 8;
      __builtin_amdgcn_global_load_lds(
        (const __attribute__((address_space(1))) unsigned int*)(qksrc + (size_t)st * 64 + 32 + gq),
        (__attribute__((address_space(3))) unsigned int*)(s_k + i * 512), 16, 0, 0);
    }
  }
  int ng = nst * 8;                // gke(128B)/v(128B): 8 granules/step
#pragma unroll
  for (int i = 0; i < 3; ++i) {
    int gi = i * 64 + lane;
    if (gi < ng) {
      __builtin_amdgcn_global_load_lds(
        (const __attribute__((address_space(1))) unsigned int*)(gsrc + (size_t)gi * 4),
        (__attribute__((address_space(3))) unsigned int*)(s_g + i * 256), 16, 0, 0);
      __builtin_amdgcn_global_load_lds(
        (const __attribute__((address_space(1))) unsigned int*)(vsrc + (size_t)gi * 8),
        (__attribute__((address_space(3))) unsigned int*)(s_v + i * 512), 16, 0, 0);
    }
  }
  float S[32];
#pragma unroll
  for (int i = 0; i < 32; ++i) S[i] = 0.f;
  float ac = 1.f;
  __syncthreads();
  for (int ts = 0; ts < nst; ++ts) {
    float vv = __half2float(s_v[ts * 64 + lane]);
    const __half2* kp = (const __half2*)&s_k[ts * 32];
#pragma unroll
    for (int j = 0; j < 8; ++j) {
      float4 gg = *(const float4*)&s_g[ts * 32 + j * 4];
      float2 k01 = __half22float2(kp[2 * j]);
      float2 k23 = __half22float2(kp[2 * j + 1]);
      S[4*j+0] = S[4*j+0] * gg.x + k01.x * vv;
      S[4*j+1] = S[4*j+1] * gg.y + k01.y * vv;
      S[4*j+2] = S[4*j+2] * gg.z + k23.x * vv;
      S[4*j+3] = S[4*j+3] * gg.w + k23.y * vv;
    }
    ac *= s_g[ts * 32 + (lane & 31)];
  }
  __half* bp = Bc + ((size_t)gid * 64 + lane) * 32;
#pragma unroll
  for (int j = 0; j < 8; ++j) {
    __half2 h01 = __floats2half2_rn(S[4*j+0], S[4*j+1]);
    __half2 h23 = __floats2half2_rn(S[4*j+2], S[4*j+3]);
    *(__half2*)(bp + j * 4)     = h01;
    *(__half2*)(bp + j * 4 + 2) = h23;
  }
  if (lane < 32) Ac[(size_t)gid * 32 + lane] = ac;
}

// ---- scan B: per (b,h) combine chunks; Bc slot c := S_init(c) (in place, fp16) ----
__global__ __launch_bounds__(64) void scanB_kernel(
    const float* __restrict__ Ac, __half* __restrict__ Bc) {
  int bh = blockIdx.x;
  int lane = threadIdx.x;
  float cur[32];
#pragma unroll
  for (int i = 0; i < 32; ++i) cur[i] = 0.f;
  __shared__ float sA[32];
  for (int c = 0; c < NCH; ++c) {
    size_t gid = (size_t)bh * NCH + c;
    __half* bp = Bc + (gid * 64 + lane) * 32;
    __syncthreads();
    if (lane < 32) sA[lane] = Ac[gid * 32 + lane];
    __syncthreads();
    float tb[32];
#pragma unroll
    for (int j = 0; j < 8; ++j) {
      float2 t01 = __half22float2(*(const __half2*)(bp + j * 4));
      float2 t23 = __half22float2(*(const __half2*)(bp + j * 4 + 2));
      tb[4*j+0] = t01.x; tb[4*j+1] = t01.y; tb[4*j+2] = t23.x; tb[4*j+3] = t23.y;
    }
#pragma unroll
    for (int j = 0; j < 8; ++j) {
      *(__half2*)(bp + j * 4)     = __floats2half2_rn(cur[4*j+0], cur[4*j+1]);
      *(__half2*)(bp + j * 4 + 2) = __floats2half2_rn(cur[4*j+2], cur[4*j+3]);
    }
#pragma unroll
    for (int i = 0; i < 32; ++i)
      cur[i] = sA[i] * cur[i] + tb[i];
  }
}

// ---- scan C: LDS-staged (fp16 q,k,v,gate; fp32 gke) re-scan from fp16 S_init, emit att ----
__global__ __launch_bounds__(64) void scanC_kernel(
    const __half* __restrict__ qkPh, const __half* __restrict__ gP,
    const float* __restrict__ gkeP, const float* __restrict__ gnw,
    const __half* __restrict__ Bc, short* __restrict__ att) {
  int gid = blockIdx.x;
  int bh = gid >> 5, c = gid & 31;
  int b = bh >> 3, hh = bh & 7;
  int lane = threadIdx.x;
  int t0 = c * CSZ;
  int nst = min(CSZ, Tsz - t0);
  __shared__ __align__(16) __half s_qk[CSZ * 64];
  __shared__ __align__(16) float  s_g[CSZ * 32];
  __shared__ __align__(16) __half s_v[CSZ * 64];
  __shared__ __align__(16) __half s_gt[CSZ * 64];
  const size_t rowbase = (size_t)bh * Tsz + t0;
  const __half* qksrc = qkPh + rowbase * 64;
  const __half* vsrc  = qkPh + (size_t)VOFFH + rowbase * 64;
  const float* gsrc   = gkeP + rowbase * 32;
  const __half* gtsrc = gP + rowbase * 64;
  int ng = nst * 8;                // 8 granules/step for qk(128B), v, gt, g
#pragma unroll
  for (int i = 0; i < 3; ++i) {
    int gi = i * 64 + lane;
    if (gi < ng) {
      __builtin_amdgcn_global_load_lds(
        (const __attribute__((address_space(1))) unsigned int*)(qksrc + (size_t)gi * 8),
        (__attribute__((address_space(3))) unsigned int*)(s_qk + i * 512), 16, 0, 0);
      __builtin_amdgcn_global_load_lds(
        (const __attribute__((address_space(1))) unsigned int*)(vsrc + (size_t)gi * 8),
        (__attribute__((address_space(3))) unsigned int*)(s_v + i * 512), 16, 0, 0);
      __builtin_amdgcn_global_load_lds(
        (const __attribute__((address_space(1))) unsigned int*)(gsrc + (size_t)gi * 4),
        (__attribute__((address_space(3))) unsigned int*)(s_g + i * 256), 16, 0, 0);
      __builtin_amdgcn_global_load_lds(
        (const __attribute__((address_space(1))) unsigned int*)(gtsrc + (size_t)gi * 8),
        (__attribute__((address_space(3))) unsigned int*)(s_gt + i * 512), 16, 0, 0);
    }
  }
  float S[32];
  const __half* sp = Bc + ((size_t)gid * 64 + lane) * 32;
#pragma unroll
  for (int j = 0; j < 8; ++j) {
    float2 s01 = __half22float2(*(const __half2*)(sp + j * 4));
    float2 s23 = __half22float2(*(const __half2*)(sp + j * 4 + 2));
    S[4*j+0] = s01.x; S[4*j+1] = s01.y; S[4*j+2] = s23.x; S[4*j+3] = s23.y;
  }
  float gn = gnw[lane];
  __syncthreads();
  for (int ts = 0; ts < nst; ++ts) {
    float vv = __half2float(s_v[ts * 64 + lane]);
    float gv = __half2float(s_gt[ts * 64 + lane]);
    const __half2* qp = (const __half2*)&s_qk[ts * 64];
    const __half2* kp = qp + 16;
    float o0 = 0.f, o1 = 0.f, o2 = 0.f, o3 = 0.f;
#pragma unroll
    for (int j = 0; j < 8; ++j) {
      float4 gg = *(const float4*)&s_g[ts * 32 + j * 4];
      float2 q01 = __half22float2(qp[2 * j]);
      float2 q23 = __half22float2(qp[2 * j + 1]);
      float2 k01 = __half22float2(kp[2 * j]);
      float2 k23 = __half22float2(kp[2 * j + 1]);
      S[4*j+0] = S[4*j+0] * gg.x + k01.x * vv;  o0 += q01.x * S[4*j+0];
      S[4*j+1] = S[4*j+1] * gg.y + k01.y * vv;  o1 += q01.y * S[4*j+1];
      S[4*j+2] = S[4*j+2] * gg.z + k23.x * vv;  o2 += q23.x * S[4*j+2];
      S[4*j+3] = S[4*j+3] * gg.w + k23.y * vv;  o3 += q23.y * S[4*j+3];
    }
    float o = ((o0 + o1) + (o2 + o3)) * 0.17677669529663689f;   // 32^-0.5
    float ss = wave_sum(o * o);
    float r = rsqrtf(ss * (1.f / 64.f) + 1e-5f);
    float sig = 1.f / (1.f + expf(-gv));
    att[((size_t)b * Tsz + t0 + ts) * DVsz + hh * HVsz + lane] = f2bf(o * r * gn * gv * sig);
  }
}

// ---- final head ----
__global__ __launch_bounds__(64) void head_kernel(
    const float* __restrict__ h, const float* __restrict__ hw,
    const float* __restrict__ hb, float* __restrict__ out) {
  int b = blockIdx.x, lane = threadIdx.x;
  const float* p = h + ((size_t)b * Tsz + Ssz) * Dsz;
  float p0 = 0.f, p1 = 0.f, p2 = 0.f;
#pragma unroll
  for (int j = 0; j < 8; ++j) {
    int d = lane + j * 64;
    float hv = p[d];
    p0 += hv * hw[d * 3 + 0];
    p1 += hv * hw[d * 3 + 1];
    p2 += hv * hw[d * 3 + 2];
  }
  p0 = wave_sum(p0); p1 = wave_sum(p1); p2 = wave_sum(p2);
  if (lane == 0) {
    out[b * 3 + 0] = p0 + hb[0];
    out[b * 3 + 1] = p1 + hb[1];
    out[b * 3 + 2] = p2 + hb[2];
  }
}

extern "C" void kernel_launch(void* const* d_in, const int* in_sizes, int n_in,
                              void* d_out, int out_size, void* d_ws, size_t ws_size,
                              hipStream_t stream) {
  const float* x       = (const float*)d_in[0];
  const float* bin_l1  = (const float*)d_in[1];
  const float* bin_b1  = (const float*)d_in[2];
  const float* bin_l2  = (const float*)d_in[3];
  const float* bin_b2  = (const float*)d_in[4];
  const float* bin_y1  = (const float*)d_in[5];
  const float* bin_y2  = (const float*)d_in[6];
  const float* emb_w   = (const float*)d_in[7];
  const float* emb_b   = (const float*)d_in[8];
  const float* cls     = (const float*)d_in[9];
  const float* ln1_w   = (const float*)d_in[10];
  const float* ln1_b   = (const float*)d_in[11];
  const float* q_w     = (const float*)d_in[12];
  const float* k_w     = (const float*)d_in[13];
  const float* v_w     = (const float*)d_in[14];
  const float* g_w     = (const float*)d_in[15];
  const float* gk_w1   = (const float*)d_in[16];
  const float* gk_w2   = (const float*)d_in[17];
  const float* gk_b2   = (const float*)d_in[18];
  const float* gnorm_w = (const float*)d_in[19];
  const float* o_w     = (const float*)d_in[20];
  const float* ln2_w   = (const float*)d_in[21];
  const float* ln2_b   = (const float*)d_in[22];
  const float* mlp_w1  = (const float*)d_in[23];
  const float* mlp_b1  = (const float*)d_in[24];
  const float* mlp_w2  = (const float*)d_in[25];
  const float* mlp_b2  = (const float*)d_in[26];
  const float* head_w  = (const float*)d_in[27];
  const float* head_b  = (const float*)d_in[28];
  float* out = (float*)d_out;

  // ---- workspace layout (~163 MB; Bc lives in the dead tail of qkP region) ----
  char* wptr = (char*)d_ws;
  auto alloc = [&](size_t bytes) { char* p = wptr; wptr += (bytes + 255) & ~(size_t)255; return p; };
  float* pos  = (float*)alloc((size_t)Tsz * Dsz * 4);
  float* h    = (float*)alloc((size_t)Mpad * Dsz * 4);
  short* xn   = (short*)alloc((size_t)Mpad * Dsz * 2);      // LN out; aliased as att
  float* qkP  = (float*)alloc((size_t)Mpad * MLPsz * 2);    // qkPh|vPh|Bc ; also xbT / mid
  float* gkeP = (float*)alloc((size_t)256 * Tsz * 32 * 4);
  __half* gP  = (__half*)alloc((size_t)256 * Tsz * 64 * 2);
  float* mt   = (float*)alloc((size_t)Bsz * Fsz * 4);
  float* rst  = (float*)alloc((size_t)Bsz * Fsz * 4);
  float* Ac   = (float*)alloc((size_t)Bsz * Hh * NCH * 32 * 4);
  short* wtr  = (short*)alloc((size_t)3145728 * 2);         // per-layer bf16 weights
  float* xbT  = qkP;             // [40][Mpad] fp32, dead before qkv GEMM
  short* mid  = (short*)qkP;     // MLP mid bf16, aliases qkPh/vPh/Bc (dead by MLP)
  short* att  = xn;              // scan output aliases xn (dead after gk12)
  __half* qkPh = (__half*)qkP;   // fp16 q|k rows; vPh = qkPh + VOFFH
  __half* Bc  = qkPh + (size_t)2 * VOFFH;   // fp16 chunk states, 33.5 MB in dead tail

  short* qkvT = wtr;                          // [1536][512]
  short* owT  = qkvT + 786432;
  short* m1T  = owT + 262144;
  short* m2T  = m1T + 1048576;

  // ---- pre ----
  hipLaunchKernelGGL(pos_kernel, dim3((Tsz * Dsz + 255) / 256), dim3(256), 0, stream, pos);
  hipLaunchKernelGGL(tstat_kernel, dim3(Bsz * Fsz), dim3(64), 0, stream, x, mt, rst);
  hipLaunchKernelGGL(binorm_kernel, dim3(Mpad), dim3(64), 0, stream,
                     x, bin_l1, bin_b1, bin_l2, bin_b2, bin_y1, bin_y2, mt, rst, xbT);
  hipLaunchKernelGGL(embgemm_kernel, dim3(258, 8), dim3(256), 0, stream,
                     xbT, emb_w, emb_b, cls, pos, h);

  dim3 blk256(256);
  for (int l = 0; l < Lnum; ++l) {
    hipLaunchKernelGGL(wtall_kernel, dim3(3072), blk256, 0, stream,
                       q_w + (size_t)l*Dsz*DKsz, k_w + (size_t)l*Dsz*DKsz,
                       v_w + (size_t)l*Dsz*DVsz, g_w + (size_t)l*Dsz*DVsz,
                       o_w + (size_t)l*DVsz*Dsz, mlp_w1 + (size_t)l*Dsz*MLPsz,
                       mlp_w2 + (size_t)l*MLPsz*Dsz, qkvT, owT, m1T, m2T);

    const float* lw1 = ln1_w + l * Dsz;  const float* lb1 = ln1_b + l * Dsz;
    const float* g1w = gk_w1 + (size_t)l * Dsz * 16;
    const float* g2w = gk_w2 + (size_t)l * 16 * DKsz;
    const float* g2b = gk_b2 + (size_t)l * DKsz;
    const float* gnw = gnorm_w + l * HVsz;
    const float* lw2 = ln2_w + l * Dsz;  const float* lb2 = ln2_b + l * Dsz;
    const float* m1b = mlp_b1 + (size_t)l * MLPsz;
    const float* m2b = mlp_b2 + (size_t)l * Dsz;

    hipLaunchKernelGGL(ln_kernel, dim3(Msz), dim3(64), 0, stream, h, lw1, lb1, xn);

    // packed q|k|v|g projection (N=1536, TN=128) with LDS-coalesced fp16 scatter
    hipLaunchKernelGGL((mgemm_kernel<0,0,1,128>), dim3(129 * 12), blk256, 0, stream,
                       xn, qkvT, (void*)qkPh, (const float*)nullptr, (const float*)gP, QKVG, Dsz);
    // merged gk low-rank path (one launch)
    hipLaunchKernelGGL(gk12_kernel, dim3(Msz), dim3(64), 0, stream, xn, g1w, g2w, g2b, gkeP);

    // chunk-parallel GLA scan (NCH=32, fp16 operands+state buffers / fp32 recurrence)
    hipLaunchKernelGGL(scanA_kernel, dim3(Bsz * Hh * NCH), dim3(64), 0, stream,
                       qkPh, gkeP, Ac, Bc);
    hipLaunchKernelGGL(scanB_kernel, dim3(Bsz * Hh), dim3(64), 0, stream, Ac, Bc);
    hipLaunchKernelGGL(scanC_kernel, dim3(Bsz * Hh * NCH), dim3(64), 0, stream,
                       qkPh, gP, gkeP, gnw, Bc, att);

    // h = h + att @ o_w   (N=512, TN=64 -> 1032 blocks)
    hipLaunchKernelGGL((mgemm_kernel<0,0,0,64>), dim3(129 * 8), blk256, 0, stream,
                       att, owT, (void*)h, (const float*)nullptr, h, Dsz, DVsz);

    hipLaunchKernelGGL(ln_kernel, dim3(Msz), dim3(64), 0, stream, h, lw2, lb2, xn);
    // mid = gelu(xn @ w1 + b1)   (bf16 out, TN=128, exact erff)
    hipLaunchKernelGGL((mgemm_kernel<1,1,0,128>), dim3(129 * 16), blk256, 0, stream,
                       xn, m1T, (void*)mid, m1b, (const float*)nullptr, MLPsz, Dsz);
    // h = h + mid @ w2 + b2   (N=512, TN=64 -> 1032 blocks)
    hipLaunchKernelGGL((mgemm_kernel<0,0,0,64>), dim3(129 * 8), blk256, 0, stream,
                       mid, m2T, (void*)h, m2b, h, Dsz, MLPsz);
  }

  hipLaunchKernelGGL(head_kernel, dim3(Bsz), dim3(64), 0, stream, h, head_w, head_b, out);
}